// Round 1
// baseline (1203.450 us; speedup 1.0000x reference)
//
#include <hip/hip_runtime.h>
#include <hip/hip_bf16.h>

// Problem constants
constexpr int kB  = 16;
constexpr int kE  = 1024;
constexpr int kH  = 16;
constexpr int kN  = 2048;
constexpr int kEh = 64;
constexpr int kBH = 256;
constexpr int kM  = kN * kB;   // 32768 rows in the out-projection GEMM

typedef __bf16 bf16x8 __attribute__((ext_vector_type(8)));
typedef float  f32x4  __attribute__((ext_vector_type(4)));

// ---------------------------------------------------------------------------
// Kernel 1: in-projection. One block per output column j of in_proj_weight
// (j in [0, 3*E)). Computes q_step (scaled by 1/sqrt(Eh)), k_step, v_step.
// ---------------------------------------------------------------------------
__global__ __launch_bounds__(256) void proj_kernel(
    const float* __restrict__ query, const float* __restrict__ key_in,
    const float* __restrict__ value, const float* __restrict__ W,
    const float* __restrict__ bias,
    float* __restrict__ q_step, float* __restrict__ k_step,
    float* __restrict__ v_step) {
  int j   = blockIdx.x;        // 0..3071
  int mat = j >> 10;           // 0=q,1=k,2=v
  int col = j & 1023;
  const float* in = (mat == 0) ? query : ((mat == 1) ? key_in : value);
  const float* wrow = W + (size_t)j * kE;

  float part[16];
#pragma unroll
  for (int r = 0; r < 16; ++r) part[r] = 0.f;

  for (int k = threadIdx.x; k < kE; k += 256) {
    float w = wrow[k];
#pragma unroll
    for (int r = 0; r < 16; ++r) part[r] += w * in[r * kE + k];
  }
  // wave reduce (lane 0 ends with the wave sum)
#pragma unroll
  for (int r = 0; r < 16; ++r) {
    float v = part[r];
    for (int off = 32; off > 0; off >>= 1) v += __shfl_down(v, off, 64);
    part[r] = v;
  }
  __shared__ float red[4][16];
  int wave = threadIdx.x >> 6;
  int lane = threadIdx.x & 63;
  if (lane == 0) {
#pragma unroll
    for (int r = 0; r < 16; ++r) red[wave][r] = part[r];
  }
  __syncthreads();
  if (threadIdx.x < 16) {
    int r = threadIdx.x;  // batch row
    float v = red[0][r] + red[1][r] + red[2][r] + red[3][r] + bias[j];
    int h = col >> 6, eh = col & 63;
    int bh = r * kH + h;
    if (mat == 0)      q_step[bh * kEh + eh] = v * 0.125f;  // 1/sqrt(64)
    else if (mat == 1) k_step[bh * kEh + eh] = v;
    else               v_step[bh * kEh + eh] = v;
  }
}

// ---------------------------------------------------------------------------
// Kernel 2: fp32 -> bf16 conversion of out_proj_weight
// ---------------------------------------------------------------------------
__global__ void wcvt_kernel(const float* __restrict__ w,
                            __hip_bfloat16* __restrict__ o, int n) {
  int i = blockIdx.x * blockDim.x + threadIdx.x;
  if (i < n) o[i] = __float2bfloat16(w[i]);
}

// ---------------------------------------------------------------------------
// Kernel 3: k_t pass. Shift k_t along N (contiguous dim), compute
// a_tb1[b,s] = exp(q_step . k_t[:, s+1]) and per-b top_sum via atomics.
// grid (kBH, 4), block 256: each block owns 512 input columns.
// ---------------------------------------------------------------------------
__global__ __launch_bounds__(256) void kt_kernel(
    const float* __restrict__ k_t_mem, const float* __restrict__ q_step,
    float* __restrict__ k_t_out, float* __restrict__ a_tb1,
    float* __restrict__ top_sum) {
  int b = blockIdx.x;
  int chunk = blockIdx.y;  // 0..3
  __shared__ float qs[64];
  if (threadIdx.x < 64) qs[threadIdx.x] = q_step[b * kEh + threadIdx.x];
  __syncthreads();

  int c0 = chunk * 512;
  int c_a = c0 + threadIdx.x;
  int c_b = c0 + 256 + threadIdx.x;
  const float* src = k_t_mem + (size_t)b * kEh * kN;
  float* dst = k_t_out + (size_t)b * kEh * kN;

  float dot0 = 0.f, dot1 = 0.f;
  for (int e = 0; e < 64; ++e) {
    float va = src[(size_t)e * kN + c_a];
    float vb = src[(size_t)e * kN + c_b];
    dot0 += qs[e] * va;
    dot1 += qs[e] * vb;
    if (c_a >= 1) dst[(size_t)e * kN + c_a - 1] = va;
    dst[(size_t)e * kN + c_b - 1] = vb;  // c_b >= 256 always
  }
  float t0 = (c_a >= 1) ? __expf(dot0) : 0.f;
  float t1 = __expf(dot1);
  if (c_a >= 1) a_tb1[(size_t)b * (kN - 1) + c_a - 1] = t0;
  a_tb1[(size_t)b * (kN - 1) + c_b - 1] = t1;

  float s = t0 + t1;
  for (int off = 32; off > 0; off >>= 1) s += __shfl_xor(s, off, 64);
  __shared__ float red[4];
  int wave = threadIdx.x >> 6, lane = threadIdx.x & 63;
  if (lane == 0) red[wave] = s;
  __syncthreads();
  if (threadIdx.x == 0)
    atomicAdd(&top_sum[b], red[0] + red[1] + red[2] + red[3]);
}

// ---------------------------------------------------------------------------
// Kernel 4: q/av pass. One wave per row j (j in [0, N-2]); lane = element.
// Computes a_lr0/a_lr1, a_sum, av update, attn bf16 row; shifts q_mem.
// grid (kBH, 64), block 256: 4 waves x 8 rows each.
// ---------------------------------------------------------------------------
__global__ __launch_bounds__(256) void qav_kernel(
    const float* __restrict__ q_mem, const float* __restrict__ av_mem,
    const float* __restrict__ a_sum_mem, const float* __restrict__ k_t_mem,
    const float* __restrict__ v_mem, const float* __restrict__ k_step,
    const float* __restrict__ v_step, float* __restrict__ q_out,
    float* __restrict__ av_out, float* __restrict__ a_sum_out,
    __hip_bfloat16* __restrict__ attn) {
  int b = blockIdx.x;
  int chunk = blockIdx.y;  // 0..63
  int wave = threadIdx.x >> 6, lane = threadIdx.x & 63;
  int b_ = b >> 4, h = b & 15;

  float kold = k_t_mem[(size_t)b * kEh * kN + (size_t)lane * kN];  // col 0
  float kst  = k_step[b * kEh + lane];
  float vold = v_mem[(size_t)b * kN * kEh + lane];  // row 0
  float vst  = v_step[b * kEh + lane];

  int j0 = chunk * 32 + wave * 8;
  for (int jj = 0; jj < 8; ++jj) {
    int j = j0 + jj;
    if (j > kN - 2) break;  // j in 0..2046
    float qv = q_mem[((size_t)b * kN + (j + 1)) * kEh + lane];
    float p0 = qv * kold;
    float p1 = qv * kst;
    for (int off = 32; off > 0; off >>= 1) {
      p0 += __shfl_xor(p0, off, 64);
      p1 += __shfl_xor(p1, off, 64);
    }
    float a0 = __expf(p0);
    float a1 = __expf(p1);
    q_out[((size_t)b * kN + j) * kEh + lane] = qv;
    float asum = a_sum_mem[(size_t)b * (kN - 1) + j] + a1 - a0;
    float avv = av_mem[((size_t)b * (kN - 1) + j) * kEh + lane]
                - a0 * vold + a1 * vst;
    attn[((size_t)j * kB + b_) * kE + h * kEh + lane] =
        __float2bfloat16(avv / asum);
    if (j >= 1) {
      if (lane == 0) a_sum_out[(size_t)b * (kN - 1) + (j - 1)] = asum;
      av_out[((size_t)b * (kN - 1) + (j - 1)) * kEh + lane] = avv;
    }
  }
}

// ---------------------------------------------------------------------------
// Kernel 5: v pass. Shift v_mem rows; accumulate av_last = sum_s a_tb1*v row.
// grid (kBH, 8), block 256: 4 waves x 64 rows each.
// ---------------------------------------------------------------------------
__global__ __launch_bounds__(256) void v_kernel(
    const float* __restrict__ v_mem, const float* __restrict__ a_tb1,
    float* __restrict__ v_out, float* __restrict__ av_last) {
  int b = blockIdx.x;
  int chunk = blockIdx.y;  // 0..7
  int wave = threadIdx.x >> 6, lane = threadIdx.x & 63;
  const float* vsrc = v_mem + (size_t)b * kN * kEh;
  float* vdst = v_out + (size_t)b * kN * kEh;
  const float* tb = a_tb1 + (size_t)b * (kN - 1);

  float acc = 0.f;
  int s0 = chunk * 256 + wave * 64;
  for (int ss = 0; ss < 64; ++ss) {
    int s = s0 + ss;
    if (s > kN - 2) break;  // s in 0..2046
    float t = tb[s];
    float vv = vsrc[(size_t)(s + 1) * kEh + lane];
    acc += t * vv;
    vdst[(size_t)s * kEh + lane] = vv;
  }
  __shared__ float red[4][64];
  red[wave][lane] = acc;
  __syncthreads();
  if (wave == 0) {
    float a = red[0][lane] + red[1][lane] + red[2][lane] + red[3][lane];
    atomicAdd(&av_last[b * kEh + lane], a);
  }
}

// ---------------------------------------------------------------------------
// Kernel 6: finalize. Last row/column of all states + attn last row.
// grid kBH, block 64.
// ---------------------------------------------------------------------------
__global__ __launch_bounds__(64) void final_kernel(
    const float* __restrict__ q_step, const float* __restrict__ k_step,
    const float* __restrict__ v_step, const float* __restrict__ top_sum,
    const float* __restrict__ av_last_in, float* __restrict__ q_out,
    float* __restrict__ k_t_out, float* __restrict__ v_out,
    float* __restrict__ a_sum_out, float* __restrict__ av_out,
    __hip_bfloat16* __restrict__ attn) {
  int b = blockIdx.x;
  int lane = threadIdx.x;
  int b_ = b >> 4, h = b & 15;
  float qs = q_step[b * kEh + lane];
  float ks = k_step[b * kEh + lane];
  float vs = v_step[b * kEh + lane];
  float p = qs * ks;
  for (int off = 32; off > 0; off >>= 1) p += __shfl_xor(p, off, 64);
  float abr = __expf(p);
  float asum = top_sum[b] + abr;
  float avl = av_last_in[b * kEh + lane] + abr * vs;
  attn[((size_t)(kN - 1) * kB + b_) * kE + h * kEh + lane] =
      __float2bfloat16(avl / asum);
  if (lane == 0) a_sum_out[(size_t)b * (kN - 1) + (kN - 2)] = asum;
  av_out[((size_t)b * (kN - 1) + (kN - 2)) * kEh + lane] = avl;
  q_out[((size_t)b * kN + (kN - 1)) * kEh + lane] = qs;
  k_t_out[(size_t)b * kEh * kN + (size_t)lane * kN + (kN - 1)] = ks;
  v_out[((size_t)b * kN + (kN - 1)) * kEh + lane] = vs;
}

// ---------------------------------------------------------------------------
// Kernel 7: out-projection GEMM. C(M x 1024) = A(M x 1024 bf16) * W^T + bias.
// 128x128 tile, BK=64, 4 waves, 16x16x32 bf16 MFMA, global_load_lds width 16.
// ---------------------------------------------------------------------------
#define BM 128
#define BN 128
#define BK 64

__global__ __launch_bounds__(256) void gemm_kernel(
    const __bf16* __restrict__ A, const __bf16* __restrict__ Bw,
    const float* __restrict__ bias, float* __restrict__ C,
    int M, int Ncols, int K) {
  __shared__ __bf16 lA[BM * BK];  // 16 KB
  __shared__ __bf16 lB[BN * BK];  // 16 KB
  int tid = threadIdx.x;
  int m0 = blockIdx.x * BM;
  int n0 = blockIdx.y * BN;
  int wave = tid >> 6;
  int lane = tid & 63;
  int wm = (wave & 1) * 64;
  int wn = (wave >> 1) * 64;

  f32x4 zero = {0.f, 0.f, 0.f, 0.f};
  f32x4 acc[4][4];
#pragma unroll
  for (int i = 0; i < 4; ++i)
#pragma unroll
    for (int j = 0; j < 4; ++j) acc[i][j] = zero;

  int quad = lane >> 4;
  int mrow = lane & 15;

  for (int k0 = 0; k0 < K; k0 += BK) {
#pragma unroll
    for (int r = 0; r < 4; ++r) {
      int off = r * 4096 + tid * 16;  // byte offset inside tile
      int row = off >> 7;             // 0..127 (row = 128 B)
      int col8 = (off >> 4) & 7;      // 16B chunk within row
      const __bf16* ga = A + ((size_t)(m0 + row) * K + k0 + col8 * 8);
      const __bf16* gb = Bw + ((size_t)(n0 + row) * K + k0 + col8 * 8);
      __builtin_amdgcn_global_load_lds(
          (const __attribute__((address_space(1))) void*)ga,
          (__attribute__((address_space(3))) void*)((char*)lA + off), 16, 0, 0);
      __builtin_amdgcn_global_load_lds(
          (const __attribute__((address_space(1))) void*)gb,
          (__attribute__((address_space(3))) void*)((char*)lB + off), 16, 0, 0);
    }
    __syncthreads();

#pragma unroll
    for (int kk = 0; kk < 2; ++kk) {
      bf16x8 af[4], bfr[4];
#pragma unroll
      for (int i = 0; i < 4; ++i) {
        af[i]  = *(const bf16x8*)(&lA[(wm + i * 16 + mrow) * BK + kk * 32 + quad * 8]);
        bfr[i] = *(const bf16x8*)(&lB[(wn + i * 16 + mrow) * BK + kk * 32 + quad * 8]);
      }
#pragma unroll
      for (int i = 0; i < 4; ++i)
#pragma unroll
        for (int j = 0; j < 4; ++j)
          acc[i][j] = __builtin_amdgcn_mfma_f32_16x16x32_bf16(
              af[i], bfr[j], acc[i][j], 0, 0, 0);
    }
    __syncthreads();
  }

  // epilogue: C/D layout col=lane&15, row=(lane>>4)*4+reg
  int colq = lane & 15;
  int rowq = lane >> 4;
#pragma unroll
  for (int i = 0; i < 4; ++i) {
#pragma unroll
    for (int j = 0; j < 4; ++j) {
      int col = n0 + wn + j * 16 + colq;
      float bv = bias[col];
      size_t base = (size_t)(m0 + wm + i * 16 + rowq * 4) * Ncols + col;
#pragma unroll
      for (int r = 0; r < 4; ++r) {
        C[base + (size_t)r * Ncols] = acc[i][j][r] + bv;
      }
    }
  }
}

// ---------------------------------------------------------------------------
// Launch
// ---------------------------------------------------------------------------
extern "C" void kernel_launch(void* const* d_in, const int* in_sizes, int n_in,
                              void* d_out, int out_size, void* d_ws,
                              size_t ws_size, hipStream_t stream) {
  const float* query          = (const float*)d_in[0];
  const float* key_in         = (const float*)d_in[1];
  const float* value          = (const float*)d_in[2];
  const float* a_sum_mem      = (const float*)d_in[3];
  const float* av_mem         = (const float*)d_in[4];
  const float* q_mem          = (const float*)d_in[5];
  const float* k_t_mem        = (const float*)d_in[6];
  const float* v_mem          = (const float*)d_in[7];
  const float* in_proj_weight = (const float*)d_in[8];
  const float* in_proj_bias   = (const float*)d_in[9];
  const float* out_proj_weight= (const float*)d_in[10];
  const float* out_proj_bias  = (const float*)d_in[11];

  // Output layout (flat fp32, return order)
  float* out       = (float*)d_out;                          // N*B*E
  float* a_sum_out = out + (size_t)kN * kB * kE;             // BH*(N-1)
  float* av_out    = a_sum_out + (size_t)kBH * (kN - 1);     // BH*(N-1)*Eh
  float* q_out     = av_out + (size_t)kBH * (kN - 1) * kEh;  // BH*N*Eh
  float* k_t_out   = q_out + (size_t)kBH * kN * kEh;         // BH*Eh*N
  float* v_out     = k_t_out + (size_t)kBH * kEh * kN;       // BH*N*Eh

  // Workspace layout
  char* ws = (char*)d_ws;
  float* q_step  = (float*)ws;              // 16384 f
  float* k_step  = q_step + 16384;          // 16384 f
  float* v_step  = k_step + 16384;          // 16384 f
  float* top_sum = v_step + 16384;          // 256 f   (zeroed)
  float* av_last = top_sum + 256;           // 16384 f (zeroed)
  float* a_tb1   = av_last + 16384;         // 524032 f
  __hip_bfloat16* wo_bf   = (__hip_bfloat16*)(ws + 2359296);  // 1M bf16
  __hip_bfloat16* attn_bf = (__hip_bfloat16*)(ws + 4456448);  // 32M bf16

  // zero the atomic accumulators (top_sum + av_last = 16640 floats)
  hipMemsetAsync(ws + 196608, 0, 66560, stream);

  proj_kernel<<<3 * kE, 256, 0, stream>>>(query, key_in, value, in_proj_weight,
                                          in_proj_bias, q_step, k_step, v_step);
  wcvt_kernel<<<(kE * kE) / 256, 256, 0, stream>>>(out_proj_weight, wo_bf,
                                                   kE * kE);
  kt_kernel<<<dim3(kBH, 4), 256, 0, stream>>>(k_t_mem, q_step, k_t_out, a_tb1,
                                              top_sum);
  qav_kernel<<<dim3(kBH, 64), 256, 0, stream>>>(q_mem, av_mem, a_sum_mem,
                                                k_t_mem, v_mem, k_step, v_step,
                                                q_out, av_out, a_sum_out,
                                                attn_bf);
  v_kernel<<<dim3(kBH, 8), 256, 0, stream>>>(v_mem, a_tb1, v_out, av_last);
  final_kernel<<<kBH, 64, 0, stream>>>(q_step, k_step, v_step, top_sum,
                                       av_last, q_out, k_t_out, v_out,
                                       a_sum_out, av_out, attn_bf);
  gemm_kernel<<<dim3(kM / BM, kE / BN), 256, 0, stream>>>(
      (const __bf16*)attn_bf, (const __bf16*)wo_bf, out_proj_bias, out, kM, kE,
      kE);
}